// Round 5
// baseline (1396.763 us; speedup 1.0000x reference)
//
#include <hip/hip_runtime.h>
#include <stdint.h>

typedef unsigned short u16;

#define HIDDEN 128   // NH(8) * HD(16)
#define NB 32        // nodes per GEMM block

// INPUTS fp32, OUTPUT fp32 (both confirmed by round 3->4 error collapse).
// Intermediates W/Q/K/V stored FP16 (bf16 was 0.125 err vs 0.105 threshold;
// fp16 is 8x finer). All arithmetic fp32.

__device__ __forceinline__ float h2f(u16 u) {
    _Float16 h; __builtin_memcpy(&h, &u, 2); return (float)h;
}
__device__ __forceinline__ u16 f2h(float f) {
    _Float16 h = (_Float16)f; u16 u; __builtin_memcpy(&u, &h, 2); return u;
}

// ---------------------------------------------------------------------------
// VALU QKV projection. Block = 256 threads, NB=32 nodes.
// LDS: all 3 W as fp16 (96KB) + h fp32 (16KB). Lane owns cols {2l, 2l+1};
// h[k] is an LDS broadcast (wave-uniform).
// ---------------------------------------------------------------------------
__global__ __launch_bounds__(256) void qkv_gemm_valu(
    const float* __restrict__ h,
    const float* __restrict__ Wq, const float* __restrict__ Wk, const float* __restrict__ Wv,
    const float* __restrict__ bq, const float* __restrict__ bk, const float* __restrict__ bv,
    u16* __restrict__ Qb, u16* __restrict__ Kb, u16* __restrict__ Vb, int n) {
    __shared__ u16   lds_w[3 * HIDDEN * HIDDEN];   // 96 KB, [w][k][c]
    __shared__ float lds_h[NB * HIDDEN];           // 16 KB

    int t = threadIdx.x;
    // Stage W -> fp16 LDS (coalesced fp32 reads)
    #pragma unroll
    for (int it = 0; it < 192; ++it) {
        int idx = it * 256 + t;                    // 0..49151
        int w   = idx >> 14, rem = idx & 16383;
        const float* W = (w == 0) ? Wq : (w == 1) ? Wk : Wv;
        lds_w[idx] = f2h(W[rem]);
    }
    // Stage h rows
    int node0 = blockIdx.x * NB;
    #pragma unroll
    for (int it = 0; it < NB * HIDDEN / 256; ++it) {
        int idx = it * 256 + t;
        int row = node0 + (idx >> 7);
        lds_h[idx] = (row < n) ? h[(size_t)row * HIDDEN + (idx & 127)] : 0.f;
    }
    __syncthreads();

    int wave = t >> 6, lane = t & 63;
    int c = lane * 2;
    float bQ0 = bq[c], bQ1 = bq[c + 1];
    float bK0 = bk[c], bK1 = bk[c + 1];
    float bV0 = bv[c], bV1 = bv[c + 1];

    for (int ni = 0; ni < 8; ++ni) {
        int nl = wave * 8 + ni;
        int node = node0 + nl;
        if (node >= n) break;
        const float* hp = &lds_h[nl * HIDDEN];
        float aq0 = 0, aq1 = 0, ak0 = 0, ak1 = 0, av0 = 0, av1 = 0;
        #pragma unroll 4
        for (int k = 0; k < HIDDEN; ++k) {
            float hk = hp[k];
            uint32_t pq = *(const uint32_t*)&lds_w[        k * HIDDEN + c];
            uint32_t pk = *(const uint32_t*)&lds_w[16384 + k * HIDDEN + c];
            uint32_t pv = *(const uint32_t*)&lds_w[32768 + k * HIDDEN + c];
            aq0 += hk * h2f((u16)pq);  aq1 += hk * h2f((u16)(pq >> 16));
            ak0 += hk * h2f((u16)pk);  ak1 += hk * h2f((u16)(pk >> 16));
            av0 += hk * h2f((u16)pv);  av1 += hk * h2f((u16)(pv >> 16));
        }
        size_t base = (size_t)node * HIDDEN + c;
        *(uint32_t*)(Qb + base) = ((uint32_t)f2h(aq1 + bQ1) << 16) | f2h(aq0 + bQ0);
        *(uint32_t*)(Kb + base) = ((uint32_t)f2h(ak1 + bK1) << 16) | f2h(ak0 + bK0);
        *(uint32_t*)(Vb + base) = ((uint32_t)f2h(av1 + bV1) << 16) | f2h(av0 + bV0);
    }
}

// ---------------------------------------------------------------------------
// CSR build: histogram of dst, exclusive scan, scatter (post-increments
// offsets in place; attn recovers start = offsets[d] - counts[d]).
// ---------------------------------------------------------------------------
__global__ void count_kernel(const int* __restrict__ dst, int* __restrict__ counts, int e) {
    int i = blockIdx.x * blockDim.x + threadIdx.x;
    if (i < e) atomicAdd(&counts[dst[i]], 1);
}

__global__ __launch_bounds__(256) void scan_kernel(const int* __restrict__ counts,
                                                   int* __restrict__ offsets, int n) {
    __shared__ int totals[256];
    __shared__ int bases[256];
    int t = threadIdx.x;
    int chunk = (n + 255) / 256;
    int begin = t * chunk;
    int end = begin + chunk; if (end > n) end = n;
    if (begin > n) begin = n;
    int s = 0;
    for (int i = begin; i < end; ++i) { offsets[i] = s; s += counts[i]; }
    totals[t] = s;
    __syncthreads();
    if (t == 0) {
        int acc = 0;
        for (int i = 0; i < 256; ++i) { bases[i] = acc; acc += totals[i]; }
        offsets[n] = acc;
    }
    __syncthreads();
    int b = bases[t];
    for (int i = begin; i < end; ++i) offsets[i] += b;
}

__global__ void scatter_kernel(const int* __restrict__ src, const int* __restrict__ dst,
                               int* __restrict__ offsets, int* __restrict__ srcperm, int e) {
    int i = blockIdx.x * blockDim.x + threadIdx.x;
    if (i < e) {
        int p = atomicAdd(&offsets[dst[i]], 1);
        if (p >= 0 && p < e) srcperm[p] = src[i];
    }
}

// ---------------------------------------------------------------------------
// One wave per dst node: online softmax over incident edges.
// Lane i owns dims {2i, 2i+1}; per-head (16-dim) score reduce via
// shfl_xor(1,2,4) inside each 8-lane group. Output written fp32.
// ---------------------------------------------------------------------------
__global__ __launch_bounds__(256) void attn_kernel(
    const u16* __restrict__ Qb, const u16* __restrict__ Kb, const u16* __restrict__ Vb,
    const int* __restrict__ offsets, const int* __restrict__ counts,
    const int* __restrict__ srcperm, float* __restrict__ out, int n, int e) {
    int node = blockIdx.x * 4 + (threadIdx.x >> 6);
    int lane = threadIdx.x & 63;
    if (node >= n) return;

    uint32_t qp = *(const uint32_t*)(Qb + (size_t)node * HIDDEN + lane * 2);
    float q0 = h2f((u16)(qp & 0xffff)), q1 = h2f((u16)(qp >> 16));

    int deg = counts[node];
    if (deg < 0) deg = 0; if (deg > e) deg = e;          // defensive (no-op when correct)
    int off = offsets[node] - deg;                       // offsets was post-incremented
    if (off < 0) off = 0; if (off > e - deg) off = e - deg;

    float mrun = -INFINITY, lrun = 0.f, o0 = 0.f, o1 = 0.f;
    for (int t = 0; t < deg; ++t) {
        int s = srcperm[off + t];
        if (s < 0) s = 0; if (s >= n) s = n - 1;         // defensive (no-op when correct)
        uint32_t kp = *(const uint32_t*)(Kb + (size_t)s * HIDDEN + lane * 2);
        uint32_t vp = *(const uint32_t*)(Vb + (size_t)s * HIDDEN + lane * 2);
        float k0 = h2f((u16)(kp & 0xffff)), k1 = h2f((u16)(kp >> 16));
        float v0 = h2f((u16)(vp & 0xffff)), v1 = h2f((u16)(vp >> 16));

        float p = q0 * k0 + q1 * k1;
        p += __shfl_xor(p, 1);
        p += __shfl_xor(p, 2);
        p += __shfl_xor(p, 4);      // head score, replicated across its 8 lanes

        float mn    = fmaxf(mrun, p);
        float scale = __expf(mrun - mn);   // first iter: expf(-inf) -> 0
        float w     = __expf(p - mn);
        lrun = lrun * scale + w;
        o0   = o0 * scale + w * v0;
        o1   = o1 * scale + w * v1;
        mrun = mn;
    }
    float inv = (lrun > 0.f) ? 1.f / lrun : 0.f;
    float2 r = make_float2(o0 * inv, o1 * inv);
    *(float2*)(out + (size_t)node * HIDDEN + lane * 2) = r;
}

// ---------------------------------------------------------------------------
extern "C" void kernel_launch(void* const* d_in, const int* in_sizes, int n_in,
                              void* d_out, int out_size, void* d_ws, size_t ws_size,
                              hipStream_t stream) {
    const float* h   = (const float*)d_in[0];
    const int*   src = (const int*)d_in[1];
    const int*   dst = (const int*)d_in[2];
    const float* Wq  = (const float*)d_in[3];
    const float* bq  = (const float*)d_in[4];
    const float* Wk  = (const float*)d_in[5];
    const float* bk  = (const float*)d_in[6];
    const float* Wv  = (const float*)d_in[7];
    const float* bv  = (const float*)d_in[8];
    float* out = (float*)d_out;

    const int n = in_sizes[0] / HIDDEN;   // 100000
    const int e = in_sizes[1];            // 1600000

    // Workspace carve — total ~83.6 MB.
    char* ws = (char*)d_ws;
    auto align256 = [](size_t x) { return (x + 255) & ~(size_t)255; };
    int* counts  = (int*)ws; ws += align256((size_t)n * 4);
    int* offsets = (int*)ws; ws += align256((size_t)(n + 1) * 4);
    int* srcperm = (int*)ws; ws += align256((size_t)e * 4);
    size_t nb = (size_t)n * HIDDEN * sizeof(u16);
    u16* Qb      = (u16*)ws; ws += align256(nb);
    u16* Kb      = (u16*)ws; ws += align256(nb);
    u16* Vb      = (u16*)ws; ws += align256(nb);

    hipMemsetAsync(counts, 0, (size_t)n * 4, stream);

    qkv_gemm_valu<<<(n + NB - 1) / NB, 256, 0, stream>>>(h, Wq, Wk, Wv, bq, bk, bv,
                                                         Qb, Kb, Vb, n);
    count_kernel<<<(e + 255) / 256, 256, 0, stream>>>(dst, counts, e);
    scan_kernel<<<1, 256, 0, stream>>>(counts, offsets, n);
    scatter_kernel<<<(e + 255) / 256, 256, 0, stream>>>(src, dst, offsets, srcperm, e);
    attn_kernel<<<(n + 3) / 4, 256, 0, stream>>>(Qb, Kb, Vb, offsets, counts, srcperm,
                                                 out, n, e);
}

// Round 6
// 813.773 us; speedup vs baseline: 1.7164x; 1.7164x over previous
//
#include <hip/hip_runtime.h>
#include <stdint.h>

typedef unsigned short u16;
typedef u16      u16x8 __attribute__((ext_vector_type(8)));
typedef _Float16 f16x8 __attribute__((ext_vector_type(8)));
typedef float    f32x4 __attribute__((ext_vector_type(4)));

#define HIDDEN 128   // NH(8) * HD(16)

// INPUTS fp32, OUTPUT fp32 (proven round 4->5). Intermediates W/Q/K/V fp16
// storage (proven: absmax 0.031 vs 0.105), all accumulation fp32.

__device__ __forceinline__ float h2f(u16 u) {
    _Float16 h; __builtin_memcpy(&h, &u, 2); return (float)h;
}
__device__ __forceinline__ u16 f2h(float f) {
    _Float16 h = (_Float16)f; u16 u; __builtin_memcpy(&u, &h, 2); return u;
}

// ---------------------------------------------------------------------------
// Pack [Wq|Wk|Wv] (128x128 row-major fp32 W[k][c]) into fp16 MFMA B-fragment
// order for mfma_f32_16x16x32_f16: lane l elem j holds
// B[k = kt*32 + (l>>4)*8 + j][c = (ct&7)*16 + (l&15)], ct = w*8 + col_tile.
// Linear index: (((ct*4 + kt)*64 + lane)*8 + j).
// ---------------------------------------------------------------------------
__global__ void pack_w_kernel(const float* __restrict__ Wq, const float* __restrict__ Wk,
                              const float* __restrict__ Wv, u16* __restrict__ packed) {
    int tid = blockIdx.x * blockDim.x + threadIdx.x;
    if (tid >= 24 * 4 * 64 * 8) return;
    int j    = tid & 7;
    int lane = (tid >> 3) & 63;
    int kt   = (tid >> 9) & 3;
    int ct   = tid >> 11;            // 0..23
    int w    = ct >> 3;
    int k    = kt * 32 + ((lane >> 4) << 3) + j;
    int c    = (ct & 7) * 16 + (lane & 15);
    const float* W = (w == 0) ? Wq : (w == 1) ? Wk : Wv;
    packed[tid] = f2h(W[k * HIDDEN + c]);
}

// ---------------------------------------------------------------------------
// MFMA QKV projection: {Q,K,V} = h @ W + b. No LDS; W read via packed frags.
// Block 256 = 4 waves; wave handles 16 rows x 384 cols (24 col-tiles x 4 K-steps).
// A-frag: A[m=lane&15][k=quad*8+j]; C/D: row=quad*4+r, col=lane&15 (HW-verified
// mappings, guide m89/m91).
// ---------------------------------------------------------------------------
__global__ __launch_bounds__(256) void qkv_gemm_mfma(
    const float* __restrict__ h, const u16* __restrict__ packed,
    const float* __restrict__ bq, const float* __restrict__ bk, const float* __restrict__ bv,
    u16* __restrict__ Qb, u16* __restrict__ Kb, u16* __restrict__ Vb, int n) {
    int wave = threadIdx.x >> 6, lane = threadIdx.x & 63;
    int row0 = blockIdx.x * 64 + wave * 16;
    int m = lane & 15, quad = lane >> 4;
    int arow = row0 + m;

    u16x8 a[4];
    if (arow < n) {
        const float* hp = h + (size_t)arow * HIDDEN + quad * 8;
        #pragma unroll
        for (int kt = 0; kt < 4; ++kt) {
            f32x4 lo = *(const f32x4*)(hp + kt * 32);
            f32x4 hi = *(const f32x4*)(hp + kt * 32 + 4);
            #pragma unroll
            for (int j = 0; j < 4; ++j) {
                a[kt][j]     = f2h(lo[j]);
                a[kt][j + 4] = f2h(hi[j]);
            }
        }
    } else {
        #pragma unroll
        for (int kt = 0; kt < 4; ++kt) a[kt] = (u16x8){0,0,0,0,0,0,0,0};
    }

    #pragma unroll
    for (int ct = 0; ct < 24; ++ct) {
        f32x4 acc = {0.f, 0.f, 0.f, 0.f};
        #pragma unroll
        for (int kt = 0; kt < 4; ++kt) {
            u16x8 b = *(const u16x8*)(packed + (((ct * 4 + kt) * 64 + lane) << 3));
            acc = __builtin_amdgcn_mfma_f32_16x16x32_f16(
                __builtin_bit_cast(f16x8, a[kt]), __builtin_bit_cast(f16x8, b),
                acc, 0, 0, 0);
        }
        int w  = ct >> 3;                 // compile-time after unroll
        int cc = (ct & 7) * 16 + m;
        u16*         op = (w == 0) ? Qb : (w == 1) ? Kb : Vb;
        const float* bp = (w == 0) ? bq : (w == 1) ? bk : bv;
        float bias = bp[cc];
        #pragma unroll
        for (int r = 0; r < 4; ++r) {
            int rr = row0 + quad * 4 + r;
            if (rr < n) op[(size_t)rr * HIDDEN + cc] = f2h(acc[r] + bias);
        }
    }
}

// ---------------------------------------------------------------------------
// CSR build: histogram of dst, exclusive scan, scatter (post-increments
// offsets in place; attn recovers start = offsets[d] - counts[d]).
// ---------------------------------------------------------------------------
__global__ void count_kernel(const int* __restrict__ dst, int* __restrict__ counts, int e) {
    int i = blockIdx.x * blockDim.x + threadIdx.x;
    if (i < e) atomicAdd(&counts[dst[i]], 1);
}

__global__ __launch_bounds__(256) void scan_kernel(const int* __restrict__ counts,
                                                   int* __restrict__ offsets, int n) {
    __shared__ int totals[256];
    __shared__ int bases[256];
    int t = threadIdx.x;
    int chunk = (n + 255) / 256;
    int begin = t * chunk;
    int end = begin + chunk; if (end > n) end = n;
    if (begin > n) begin = n;
    int s = 0;
    for (int i = begin; i < end; ++i) { offsets[i] = s; s += counts[i]; }
    totals[t] = s;
    __syncthreads();
    if (t == 0) {
        int acc = 0;
        for (int i = 0; i < 256; ++i) { bases[i] = acc; acc += totals[i]; }
        offsets[n] = acc;
    }
    __syncthreads();
    int b = bases[t];
    for (int i = begin; i < end; ++i) offsets[i] += b;
}

__global__ void scatter_kernel(const int* __restrict__ src, const int* __restrict__ dst,
                               int* __restrict__ offsets, int* __restrict__ srcperm, int e) {
    int i = blockIdx.x * blockDim.x + threadIdx.x;
    if (i < e) {
        int p = atomicAdd(&offsets[dst[i]], 1);
        if (p >= 0 && p < e) srcperm[p] = src[i];
    }
}

// ---------------------------------------------------------------------------
// One wave per dst node: online softmax over incident edges.
// Lane i owns dims {2i, 2i+1}; per-head (16-dim) score reduce via
// shfl_xor(1,2,4) inside each 8-lane group. Output written fp32.
// ---------------------------------------------------------------------------
__global__ __launch_bounds__(256) void attn_kernel(
    const u16* __restrict__ Qb, const u16* __restrict__ Kb, const u16* __restrict__ Vb,
    const int* __restrict__ offsets, const int* __restrict__ counts,
    const int* __restrict__ srcperm, float* __restrict__ out, int n, int e) {
    int node = blockIdx.x * 4 + (threadIdx.x >> 6);
    int lane = threadIdx.x & 63;
    if (node >= n) return;

    uint32_t qp = *(const uint32_t*)(Qb + (size_t)node * HIDDEN + lane * 2);
    float q0 = h2f((u16)(qp & 0xffff)), q1 = h2f((u16)(qp >> 16));

    int deg = counts[node];
    if (deg < 0) deg = 0; if (deg > e) deg = e;          // defensive (no-op when correct)
    int off = offsets[node] - deg;                       // offsets was post-incremented
    if (off < 0) off = 0; if (off > e - deg) off = e - deg;

    float mrun = -INFINITY, lrun = 0.f, o0 = 0.f, o1 = 0.f;
    for (int t = 0; t < deg; ++t) {
        int s = srcperm[off + t];
        if (s < 0) s = 0; if (s >= n) s = n - 1;         // defensive (no-op when correct)
        uint32_t kp = *(const uint32_t*)(Kb + (size_t)s * HIDDEN + lane * 2);
        uint32_t vp = *(const uint32_t*)(Vb + (size_t)s * HIDDEN + lane * 2);
        float k0 = h2f((u16)(kp & 0xffff)), k1 = h2f((u16)(kp >> 16));
        float v0 = h2f((u16)(vp & 0xffff)), v1 = h2f((u16)(vp >> 16));

        float p = q0 * k0 + q1 * k1;
        p += __shfl_xor(p, 1);
        p += __shfl_xor(p, 2);
        p += __shfl_xor(p, 4);      // head score, replicated across its 8 lanes

        float mn    = fmaxf(mrun, p);
        float scale = __expf(mrun - mn);   // first iter: expf(-inf) -> 0
        float w     = __expf(p - mn);
        lrun = lrun * scale + w;
        o0   = o0 * scale + w * v0;
        o1   = o1 * scale + w * v1;
        mrun = mn;
    }
    float inv = (lrun > 0.f) ? 1.f / lrun : 0.f;
    float2 r = make_float2(o0 * inv, o1 * inv);
    *(float2*)(out + (size_t)node * HIDDEN + lane * 2) = r;
}

// ---------------------------------------------------------------------------
extern "C" void kernel_launch(void* const* d_in, const int* in_sizes, int n_in,
                              void* d_out, int out_size, void* d_ws, size_t ws_size,
                              hipStream_t stream) {
    const float* h   = (const float*)d_in[0];
    const int*   src = (const int*)d_in[1];
    const int*   dst = (const int*)d_in[2];
    const float* Wq  = (const float*)d_in[3];
    const float* bq  = (const float*)d_in[4];
    const float* Wk  = (const float*)d_in[5];
    const float* bk  = (const float*)d_in[6];
    const float* Wv  = (const float*)d_in[7];
    const float* bv  = (const float*)d_in[8];
    float* out = (float*)d_out;

    const int n = in_sizes[0] / HIDDEN;   // 100000
    const int e = in_sizes[1];            // 1600000

    // Workspace carve — total ~83.7 MB (ws_size >= 84.5 MB proven).
    char* ws = (char*)d_ws;
    auto align256 = [](size_t x) { return (x + 255) & ~(size_t)255; };
    int* counts  = (int*)ws; ws += align256((size_t)n * 4);
    int* offsets = (int*)ws; ws += align256((size_t)(n + 1) * 4);
    int* srcperm = (int*)ws; ws += align256((size_t)e * 4);
    u16* packed  = (u16*)ws; ws += align256((size_t)24 * 4 * 64 * 8 * sizeof(u16));
    size_t nb = (size_t)n * HIDDEN * sizeof(u16);
    u16* Qb      = (u16*)ws; ws += align256(nb);
    u16* Kb      = (u16*)ws; ws += align256(nb);
    u16* Vb      = (u16*)ws; ws += align256(nb);

    hipMemsetAsync(counts, 0, (size_t)n * 4, stream);

    pack_w_kernel<<<(24 * 4 * 64 * 8 + 255) / 256, 256, 0, stream>>>(Wq, Wk, Wv, packed);
    qkv_gemm_mfma<<<(n + 63) / 64, 256, 0, stream>>>(h, packed, bq, bk, bv, Qb, Kb, Vb, n);
    count_kernel<<<(e + 255) / 256, 256, 0, stream>>>(dst, counts, e);
    scan_kernel<<<1, 256, 0, stream>>>(counts, offsets, n);
    scatter_kernel<<<(e + 255) / 256, 256, 0, stream>>>(src, dst, offsets, srcperm, e);
    attn_kernel<<<(n + 3) / 4, 256, 0, stream>>>(Qb, Kb, Vb, offsets, counts, srcperm,
                                                 out, n, e);
}

// Round 7
// 534.440 us; speedup vs baseline: 2.6135x; 1.5227x over previous
//
#include <hip/hip_runtime.h>
#include <stdint.h>

typedef unsigned short u16;
typedef u16      u16x8 __attribute__((ext_vector_type(8)));
typedef _Float16 f16x8 __attribute__((ext_vector_type(8)));
typedef float    f32x4 __attribute__((ext_vector_type(4)));

#define HIDDEN 128   // NH(8) * HD(16)

// INPUTS fp32, OUTPUT fp32 (proven). W/Q/K/V stored fp16 (absmax 0.031 vs
// 0.105 threshold), all accumulation fp32.

__device__ __forceinline__ float h2f(u16 u) {
    _Float16 h; __builtin_memcpy(&h, &u, 2); return (float)h;
}
__device__ __forceinline__ u16 f2h(float f) {
    _Float16 h = (_Float16)f; u16 u; __builtin_memcpy(&u, &h, 2); return u;
}

// ---------------------------------------------------------------------------
// Pack [Wq|Wk|Wv] (128x128 row-major fp32 W[k][c]) into fp16 MFMA B-fragment
// order for mfma_f32_16x16x32_f16: lane l elem j holds
// B[k = kt*32 + (l>>4)*8 + j][c = (ct&7)*16 + (l&15)], ct = w*8 + col_tile.
// ---------------------------------------------------------------------------
__global__ void pack_w_kernel(const float* __restrict__ Wq, const float* __restrict__ Wk,
                              const float* __restrict__ Wv, u16* __restrict__ packed) {
    int tid = blockIdx.x * blockDim.x + threadIdx.x;
    if (tid >= 24 * 4 * 64 * 8) return;
    int j    = tid & 7;
    int lane = (tid >> 3) & 63;
    int kt   = (tid >> 9) & 3;
    int ct   = tid >> 11;            // 0..23
    int w    = ct >> 3;
    int k    = kt * 32 + ((lane >> 4) << 3) + j;
    int c    = (ct & 7) * 16 + (lane & 15);
    const float* W = (w == 0) ? Wq : (w == 1) ? Wk : Wv;
    packed[tid] = f2h(W[k * HIDDEN + c]);
}

// ---------------------------------------------------------------------------
// MFMA QKV projection (HW-verified fragment mappings; confirmed by rounds 5->6
// absmax stability). Block 256 = 4 waves; wave: 16 rows x 384 cols.
// ---------------------------------------------------------------------------
__global__ __launch_bounds__(256) void qkv_gemm_mfma(
    const float* __restrict__ h, const u16* __restrict__ packed,
    const float* __restrict__ bq, const float* __restrict__ bk, const float* __restrict__ bv,
    u16* __restrict__ Qb, u16* __restrict__ Kb, u16* __restrict__ Vb, int n) {
    int wave = threadIdx.x >> 6, lane = threadIdx.x & 63;
    int row0 = blockIdx.x * 64 + wave * 16;
    int m = lane & 15, quad = lane >> 4;
    int arow = row0 + m;

    u16x8 a[4];
    if (arow < n) {
        const float* hp = h + (size_t)arow * HIDDEN + quad * 8;
        #pragma unroll
        for (int kt = 0; kt < 4; ++kt) {
            f32x4 lo = *(const f32x4*)(hp + kt * 32);
            f32x4 hi = *(const f32x4*)(hp + kt * 32 + 4);
            #pragma unroll
            for (int j = 0; j < 4; ++j) {
                a[kt][j]     = f2h(lo[j]);
                a[kt][j + 4] = f2h(hi[j]);
            }
        }
    } else {
        #pragma unroll
        for (int kt = 0; kt < 4; ++kt) a[kt] = (u16x8){0,0,0,0,0,0,0,0};
    }

    #pragma unroll
    for (int ct = 0; ct < 24; ++ct) {
        f32x4 acc = {0.f, 0.f, 0.f, 0.f};
        #pragma unroll
        for (int kt = 0; kt < 4; ++kt) {
            u16x8 b = *(const u16x8*)(packed + (((ct * 4 + kt) * 64 + lane) << 3));
            acc = __builtin_amdgcn_mfma_f32_16x16x32_f16(
                __builtin_bit_cast(f16x8, a[kt]), __builtin_bit_cast(f16x8, b),
                acc, 0, 0, 0);
        }
        int w  = ct >> 3;                 // compile-time after unroll
        int cc = (ct & 7) * 16 + m;
        u16*         op = (w == 0) ? Qb : (w == 1) ? Kb : Vb;
        const float* bp = (w == 0) ? bq : (w == 1) ? bk : bv;
        float bias = bp[cc];
        #pragma unroll
        for (int r = 0; r < 4; ++r) {
            int rr = row0 + quad * 4 + r;
            if (rr < n) op[(size_t)rr * HIDDEN + cc] = f2h(acc[r] + bias);
        }
    }
}

// ---------------------------------------------------------------------------
// CSR build: histogram, parallel 2-level scan, scatter (post-increments
// offsets; attn recovers start = offsets[d] - counts[d]).
// ---------------------------------------------------------------------------
__global__ void count_kernel(const int* __restrict__ dst, int* __restrict__ counts, int e) {
    int i = blockIdx.x * blockDim.x + threadIdx.x;
    if (i < e) atomicAdd(&counts[dst[i]], 1);
}

// Phase 1: per-block sums (block = 256 thr x 4 items = 1024 elements).
__global__ __launch_bounds__(256) void scan_partial(const int* __restrict__ counts,
                                                    int* __restrict__ blockSums, int n) {
    __shared__ int red[256];
    int t = threadIdx.x;
    int base = blockIdx.x * 1024 + t * 4;
    int s = 0;
    #pragma unroll
    for (int j = 0; j < 4; ++j) { int i = base + j; if (i < n) s += counts[i]; }
    red[t] = s;
    __syncthreads();
    #pragma unroll
    for (int off = 128; off > 0; off >>= 1) {
        if (t < off) red[t] += red[t + off];
        __syncthreads();
    }
    if (t == 0) blockSums[blockIdx.x] = red[0];
}

// Phase 2: exclusive scan of block sums (nb <= 256) + grand total -> offsets[n].
__global__ __launch_bounds__(256) void scan_blocksums(int* __restrict__ blockSums,
                                                      int* __restrict__ offsets,
                                                      int nb, int n) {
    __shared__ int buf[256];
    int t = threadIdx.x;
    int v = (t < nb) ? blockSums[t] : 0;
    buf[t] = v;
    __syncthreads();
    #pragma unroll
    for (int off = 1; off < 256; off <<= 1) {
        int x = (t >= off) ? buf[t - off] : 0;
        __syncthreads();
        buf[t] += x;
        __syncthreads();
    }
    if (t < nb) blockSums[t] = buf[t] - v;     // exclusive base for block t
    if (t == 255) offsets[n] = buf[255];       // grand total
}

// Phase 3: per-block re-scan with base.
__global__ __launch_bounds__(256) void scan_final(const int* __restrict__ counts,
                                                  const int* __restrict__ blockSums,
                                                  int* __restrict__ offsets, int n) {
    __shared__ int buf[256];
    int t = threadIdx.x;
    int base = blockIdx.x * 1024 + t * 4;
    int c[4];
    #pragma unroll
    for (int j = 0; j < 4; ++j) { int i = base + j; c[j] = (i < n) ? counts[i] : 0; }
    int tsum = c[0] + c[1] + c[2] + c[3];
    buf[t] = tsum;
    __syncthreads();
    #pragma unroll
    for (int off = 1; off < 256; off <<= 1) {
        int x = (t >= off) ? buf[t - off] : 0;
        __syncthreads();
        buf[t] += x;
        __syncthreads();
    }
    int run = blockSums[blockIdx.x] + buf[t] - tsum;
    #pragma unroll
    for (int j = 0; j < 4; ++j) {
        int i = base + j;
        if (i < n) { offsets[i] = run; run += c[j]; }
    }
}

__global__ void scatter_kernel(const int* __restrict__ src, const int* __restrict__ dst,
                               int* __restrict__ offsets, int* __restrict__ srcperm, int e) {
    int i = blockIdx.x * blockDim.x + threadIdx.x;
    if (i < e) {
        int p = atomicAdd(&offsets[dst[i]], 1);
        if (p >= 0 && p < e) srcperm[p] = src[i];
    }
}

// ---------------------------------------------------------------------------
// One wave per dst node: online softmax over incident edges.
// Lane i owns dims {2i, 2i+1}; per-head (16-dim) score reduce via
// shfl_xor(1,2,4) inside each 8-lane group. Output fp32.
// ---------------------------------------------------------------------------
__global__ __launch_bounds__(256) void attn_kernel(
    const u16* __restrict__ Qb, const u16* __restrict__ Kb, const u16* __restrict__ Vb,
    const int* __restrict__ offsets, const int* __restrict__ counts,
    const int* __restrict__ srcperm, float* __restrict__ out, int n, int e) {
    int node = blockIdx.x * 4 + (threadIdx.x >> 6);
    int lane = threadIdx.x & 63;
    if (node >= n) return;

    uint32_t qp = *(const uint32_t*)(Qb + (size_t)node * HIDDEN + lane * 2);
    float q0 = h2f((u16)(qp & 0xffff)), q1 = h2f((u16)(qp >> 16));

    int deg = counts[node];
    if (deg < 0) deg = 0; if (deg > e) deg = e;
    int off = offsets[node] - deg;                       // offsets was post-incremented
    if (off < 0) off = 0; if (off > e - deg) off = e - deg;

    float mrun = -INFINITY, lrun = 0.f, o0 = 0.f, o1 = 0.f;
    for (int t = 0; t < deg; ++t) {
        int s = srcperm[off + t];
        if (s < 0) s = 0; if (s >= n) s = n - 1;
        uint32_t kp = *(const uint32_t*)(Kb + (size_t)s * HIDDEN + lane * 2);
        uint32_t vp = *(const uint32_t*)(Vb + (size_t)s * HIDDEN + lane * 2);
        float k0 = h2f((u16)(kp & 0xffff)), k1 = h2f((u16)(kp >> 16));
        float v0 = h2f((u16)(vp & 0xffff)), v1 = h2f((u16)(vp >> 16));

        float p = q0 * k0 + q1 * k1;
        p += __shfl_xor(p, 1);
        p += __shfl_xor(p, 2);
        p += __shfl_xor(p, 4);

        float mn    = fmaxf(mrun, p);
        float scale = __expf(mrun - mn);
        float w     = __expf(p - mn);
        lrun = lrun * scale + w;
        o0   = o0 * scale + w * v0;
        o1   = o1 * scale + w * v1;
        mrun = mn;
    }
    float inv = (lrun > 0.f) ? 1.f / lrun : 0.f;
    float2 r = make_float2(o0 * inv, o1 * inv);
    *(float2*)(out + (size_t)node * HIDDEN + lane * 2) = r;
}

// ---------------------------------------------------------------------------
extern "C" void kernel_launch(void* const* d_in, const int* in_sizes, int n_in,
                              void* d_out, int out_size, void* d_ws, size_t ws_size,
                              hipStream_t stream) {
    const float* h   = (const float*)d_in[0];
    const int*   src = (const int*)d_in[1];
    const int*   dst = (const int*)d_in[2];
    const float* Wq  = (const float*)d_in[3];
    const float* bq  = (const float*)d_in[4];
    const float* Wk  = (const float*)d_in[5];
    const float* bk  = (const float*)d_in[6];
    const float* Wv  = (const float*)d_in[7];
    const float* bv  = (const float*)d_in[8];
    float* out = (float*)d_out;

    const int n = in_sizes[0] / HIDDEN;   // 100000
    const int e = in_sizes[1];            // 1600000
    const int nbScan = (n + 1023) / 1024; // 98 (<= 256 required by scan_blocksums)

    // Workspace carve — total ~83.7 MB (ws_size >= 84.5 MB proven).
    char* ws = (char*)d_ws;
    auto align256 = [](size_t x) { return (x + 255) & ~(size_t)255; };
    int* counts    = (int*)ws; ws += align256((size_t)n * 4);
    int* offsets   = (int*)ws; ws += align256((size_t)(n + 1) * 4);
    int* blockSums = (int*)ws; ws += align256((size_t)256 * 4);
    int* srcperm   = (int*)ws; ws += align256((size_t)e * 4);
    u16* packed    = (u16*)ws; ws += align256((size_t)24 * 4 * 64 * 8 * sizeof(u16));
    size_t nb = (size_t)n * HIDDEN * sizeof(u16);
    u16* Qb        = (u16*)ws; ws += align256(nb);
    u16* Kb        = (u16*)ws; ws += align256(nb);
    u16* Vb        = (u16*)ws; ws += align256(nb);

    hipMemsetAsync(counts, 0, (size_t)n * 4, stream);

    pack_w_kernel<<<(24 * 4 * 64 * 8 + 255) / 256, 256, 0, stream>>>(Wq, Wk, Wv, packed);
    qkv_gemm_mfma<<<(n + 63) / 64, 256, 0, stream>>>(h, packed, bq, bk, bv, Qb, Kb, Vb, n);
    count_kernel<<<(e + 255) / 256, 256, 0, stream>>>(dst, counts, e);
    scan_partial<<<nbScan, 256, 0, stream>>>(counts, blockSums, n);
    scan_blocksums<<<1, 256, 0, stream>>>(blockSums, offsets, nbScan, n);
    scan_final<<<nbScan, 256, 0, stream>>>(counts, blockSums, offsets, n);
    scatter_kernel<<<(e + 255) / 256, 256, 0, stream>>>(src, dst, offsets, srcperm, e);
    attn_kernel<<<(n + 3) / 4, 256, 0, stream>>>(Qb, Kb, Vb, offsets, counts, srcperm,
                                                 out, n, e);
}